// Round 6
// baseline (39.206 us; speedup 1.0000x reference)
//
#include <hip/hip_runtime.h>
#include <math.h>

#define GHM_DELTA 0.1f
#define GHM_EPS   1e-12f
#define NBINS     2048
#define K1THR     1024

__device__ __forceinline__ float softplus_ref(float x) {
    return fmaxf(x, 0.0f) + log1pf(expf(-fabsf(x)));
}
__device__ __forceinline__ float sigmoid_ref(float x) {
    return 1.0f / (1.0f + expf(-x));
}
__device__ __forceinline__ float g_of(const float* logits, const int* targets, int i) {
    return fabsf(sigmoid_ref(logits[i]) - (float)targets[i]);
}

// K1: single block. Histogram g into 2048 bins, exclusive prefix scan,
// counting-sort scatter to ws. Counts/prefix deterministic (integer sums);
// within-bin order nondeterministic but never observed (K2 sums 0/1 ints
// over bin ranges -> order-independent).
__global__ __launch_bounds__(K1THR) void ghm_build(
    const float* __restrict__ logits, const int* __restrict__ targets,
    float* __restrict__ sorted, int* __restrict__ pfx, int n)
{
    __shared__ int h[NBINS];      // histogram, then scatter offsets
    __shared__ int e[NBINS];      // exclusive prefix
    __shared__ int t2[NBINS];     // scan ping-pong
    const int tid = threadIdx.x;

    for (int b = tid; b < NBINS; b += K1THR) h[b] = 0;
    __syncthreads();

    float gv[16]; int bv[16];     // static-indexed (full unroll)
    #pragma unroll
    for (int p = 0; p < 16; ++p) {
        int idx = tid + p * K1THR;            // n == 16384 == 16*K1THR
        float g = g_of(logits, targets, idx);
        int b = (int)(g * (float)NBINS);
        b = min(NBINS - 1, max(0, b));
        gv[p] = g; bv[p] = b;
        atomicAdd(&h[b], 1);
    }
    __syncthreads();

    // Hillis-Steele inclusive scan over 2048 bins (11 ping-pong passes).
    int* src = h; int* dst = t2;
    for (int d = 1; d < NBINS; d <<= 1) {
        for (int k = tid; k < NBINS; k += K1THR)
            dst[k] = src[k] + (k >= d ? src[k - d] : 0);
        __syncthreads();
        int* tmp = src; src = dst; dst = tmp;
    }
    for (int k = tid; k < NBINS; k += K1THR) e[k] = (k > 0) ? src[k - 1] : 0;
    __syncthreads();
    for (int k = tid; k < NBINS; k += K1THR) pfx[k] = e[k];
    if (tid == 0) pfx[NBINS] = src[NBINS - 1];   // == n
    // reuse h as scatter cursors
    for (int k = tid; k < NBINS; k += K1THR) h[k] = e[k];
    __syncthreads();
    #pragma unroll
    for (int p = 0; p < 16; ++p) {
        int pos = atomicAdd(&h[bv[p]], 1);
        sorted[pos] = gv[p];
    }
}

// K2: 32 blocks x 512 threads, one i per thread. Interior bins via prefix
// lookup; boundary windows (+/-2 bins around each edge bin, covering all
// fp32 rounding slop) scanned with the EXACT brute-force predicate.
__global__ __launch_bounds__(512) void ghm_count_loss(
    const float* __restrict__ logits, const int* __restrict__ targets,
    const float* __restrict__ pos_weight,
    const float* __restrict__ sorted, const int* __restrict__ pfx,
    double* __restrict__ bpart, int n)
{
    __shared__ double red[16];
    const int tid = threadIdx.x;
    const int i = blockIdx.x * 512 + tid;

    float x  = logits[i];
    float y  = (float)targets[i];
    float gi = fabsf(sigmoid_ref(x) - y);

    int blo = (int)floorf((gi - GHM_DELTA) * (float)NBINS);
    int bhi = (int)floorf((gi + GHM_DELTA) * (float)NBINS);

    // interior bins [blo+3, bhi-3]: guaranteed predicate-true
    int il = max(0, blo + 3);
    int ih = min(NBINS - 1, bhi - 3);
    int cnt = pfx[ih + 1] - pfx[il];

    // low boundary window: bins [blo-2, blo+2] (skip if entirely below 0)
    if (blo >= -2) {
        int s0 = max(0, blo - 2);
        int s1 = blo + 2;                       // <= NBINS-1 always (gi<=1)
        for (int k = pfx[s0]; k < pfx[s1 + 1]; ++k)
            cnt += (fabsf(gi - sorted[k]) <= GHM_DELTA) ? 1 : 0;
    }
    // high boundary window: bins [bhi-2, bhi+2] (skip if entirely above top)
    if (bhi - 2 <= NBINS - 1) {
        int s0 = max(0, bhi - 2);
        int s1 = min(NBINS - 1, bhi + 2);
        for (int k = pfx[s0]; k < pfx[s1 + 1]; ++k)
            cnt += (fabsf(gi - sorted[k]) <= GHM_DELTA) ? 1 : 0;
    }

    float GD   = (float)cnt / GHM_DELTA;
    float beta = (float)n / (GD + GHM_EPS);
    float pw   = pos_weight[0];
    float per  = pw * y * softplus_ref(-x) + (1.0f - y) * softplus_ref(x);
    double wd = (double)(beta * per);
    double pd = (double)per;

    #pragma unroll
    for (int off = 32; off >= 1; off >>= 1) {
        wd += __shfl_down(wd, off, 64);
        pd += __shfl_down(pd, off, 64);
    }
    const int wave = tid >> 6;
    if ((tid & 63) == 0) { red[wave * 2] = wd; red[wave * 2 + 1] = pd; }
    __syncthreads();
    if (tid == 0) {
        double sw = 0.0, sp = 0.0;
        #pragma unroll
        for (int k = 0; k < 8; ++k) { sw += red[2 * k]; sp += red[2 * k + 1]; }
        bpart[blockIdx.x * 2]     = sw;
        bpart[blockIdx.x * 2 + 1] = sp;
    }
}

// K3: single-wave deterministic final reduce of 32 block partials.
__global__ __launch_bounds__(64) void ghm_reduce(
    const double* __restrict__ bpart, float* __restrict__ out, int nb, int n)
{
    double sw = 0.0, sp = 0.0;
    for (int k = threadIdx.x; k < nb; k += 64) {
        sw += bpart[2 * k];
        sp += bpart[2 * k + 1];
    }
    #pragma unroll
    for (int off = 32; off >= 1; off >>= 1) {
        sw += __shfl_down(sw, off, 64);
        sp += __shfl_down(sp, off, 64);
    }
    if (threadIdx.x == 0) {
        out[0] = (float)(sw / (double)n);
        out[1] = (float)(sp / (double)n);
    }
}

extern "C" void kernel_launch(void* const* d_in, const int* in_sizes, int n_in,
                              void* d_out, int out_size, void* d_ws, size_t ws_size,
                              hipStream_t stream) {
    const float* logits     = (const float*)d_in[0];
    const int*   targets    = (const int*)d_in[1];
    const float* pos_weight = (const float*)d_in[2];
    float* out = (float*)d_out;
    const int n = in_sizes[0];               // 16384

    // ws: sorted[n] f32 | pfx[NBINS+1] int | bpart[(n/512)*2] double
    float*  sorted = (float*)d_ws;
    int*    pfx    = (int*)((char*)d_ws + (size_t)n * sizeof(float));
    double* bpart  = (double*)((char*)d_ws + (size_t)n * sizeof(float)
                               + (NBINS + 1) * sizeof(int) + 56 /* align 8 */);
    bpart = (double*)(((uintptr_t)bpart) & ~(uintptr_t)7);

    const int nb2 = n / 512;                 // 32
    ghm_build<<<1, K1THR, 0, stream>>>(logits, targets, sorted, pfx, n);
    ghm_count_loss<<<nb2, 512, 0, stream>>>(logits, targets, pos_weight,
                                            sorted, pfx, bpart, n);
    ghm_reduce<<<1, 64, 0, stream>>>(bpart, out, nb2, n);
}